// Round 7
// baseline (360.086 us; speedup 1.0000x reference)
//
#include <hip/hip_runtime.h>

typedef short v8s __attribute__((ext_vector_type(8)));
typedef float v4f __attribute__((ext_vector_type(4)));

#define LSEQ   4096
#define BATCH  4
#define NDIM   384
#define DIN    768
#define DST    16
#define DTR    24
#define NTOK   (BATCH * LSEQ)   // 16384
#define NCHUNK 128
#define CLEN   32
#define CT     8                // tokens per thread in conv

__device__ __forceinline__ float b2f(unsigned short u) {
  unsigned int v = ((unsigned int)u) << 16;
  float f; __builtin_memcpy(&f, &v, 4); return f;
}
__device__ __forceinline__ float blo(unsigned int w) {
  unsigned int v = w << 16; float f; __builtin_memcpy(&f, &v, 4); return f;
}
__device__ __forceinline__ float bhi(unsigned int w) {
  unsigned int v = w & 0xffff0000u; float f; __builtin_memcpy(&f, &v, 4); return f;
}
__device__ __forceinline__ unsigned short f2b(float f) {
  unsigned int x; __builtin_memcpy(&x, &f, 4);
  unsigned int r = x + 0x7FFFu + ((x >> 16) & 1u);
  return (unsigned short)(r >> 16);
}
__device__ __forceinline__ void gl2lds16(const void* g, void* l) {
  __builtin_amdgcn_global_load_lds(
      (const __attribute__((address_space(1))) void*)g,
      (__attribute__((address_space(3))) void*)l, 16, 0, 0);
}

// ---------------- K0: cast GEMM weights f32 -> bf16 (+ W_dt zero-pad 24->32) --
__global__ __launch_bounds__(256) void cast_w(
    const float* __restrict__ a, unsigned short* __restrict__ oa, int na,
    const float* __restrict__ b, unsigned short* __restrict__ ob, int nb,
    const float* __restrict__ c, unsigned short* __restrict__ oc, int nc,
    const float* __restrict__ wdt, unsigned short* __restrict__ odt)
{
  int i = blockIdx.x * 256 + threadIdx.x;
  if (i < na) oa[i] = f2b(a[i]);
  if (i < nb) ob[i] = f2b(b[i]);
  if (i < nc) oc[i] = f2b(c[i]);
  if (i < DIN * 32) {
    int n = i >> 5, r = i & 31;
    odt[i] = (r < DTR) ? f2b(wdt[n * DTR + r]) : (unsigned short)0;
  }
}

// ---------------- K1a: LN stats: mu, rs per token -----------------------------
__global__ __launch_bounds__(256) void ln_stats(
    const float* __restrict__ x, float* __restrict__ mu, float* __restrict__ rs)
{
  __shared__ float red[512];
  int blk = blockIdx.x;
  int b = blk >> 7, lc = blk & 127;
  int l0 = lc * 32;
  int t = threadIdx.x;
  int lt = t & 31, part = t >> 5;   // 8 parts, 48 channels each
  float s = 0.f, ss = 0.f;
  for (int c = part; c < NDIM; c += 8) {
    float v = x[((size_t)b * NDIM + c) * LSEQ + l0 + lt];
    s += v; ss += v * v;
  }
  red[part * 32 + lt] = s;
  red[256 + part * 32 + lt] = ss;
  __syncthreads();
  if (t < 32) {
    float sum = 0.f, ssum = 0.f;
    #pragma unroll
    for (int k = 0; k < 8; k++) { sum += red[k * 32 + t]; ssum += red[256 + k * 32 + t]; }
    float m = sum / (float)NDIM;
    float var = ssum / (float)NDIM - m * m;
    mu[(size_t)b * LSEQ + l0 + t] = m;
    rs[(size_t)b * LSEQ + l0 + t] = rsqrtf(var + 1e-5f);
  }
}

// ---------------- K1b: LN apply + transpose: (B,C,L) f32 -> (B*L,C) bf16 ------
__global__ __launch_bounds__(256) void ln_apply(
    const float* __restrict__ x, const float* __restrict__ mu,
    const float* __restrict__ rs, const float* __restrict__ gamma,
    const float* __restrict__ beta, unsigned short* __restrict__ xn)
{
  __shared__ unsigned short tile[64 * 66];
  int blk = blockIdx.x;
  int ltb = blk & 63, ct = (blk >> 6) % 6, b = blk / (6 * 64);
  int l0 = ltb * 64, c0 = ct * 64;
  int t = threadIdx.x;
  int col = (t & 15) * 4;
  float4 mu4 = *(const float4*)(mu + (size_t)b * LSEQ + l0 + col);
  float4 rs4 = *(const float4*)(rs + (size_t)b * LSEQ + l0 + col);
  #pragma unroll
  for (int p = 0; p < 4; p++) {
    int row = (t >> 4) + p * 16;
    float g = gamma[c0 + row], be = beta[c0 + row];
    float4 v = *(const float4*)(x + ((size_t)b * NDIM + c0 + row) * LSEQ + l0 + col);
    unsigned int u0 = (unsigned int)f2b((v.x - mu4.x) * rs4.x * g + be)
                    | ((unsigned int)f2b((v.y - mu4.y) * rs4.y * g + be) << 16);
    unsigned int u1 = (unsigned int)f2b((v.z - mu4.z) * rs4.z * g + be)
                    | ((unsigned int)f2b((v.w - mu4.w) * rs4.w * g + be) << 16);
    *(unsigned int*)&tile[row * 66 + col]     = u0;
    *(unsigned int*)&tile[row * 66 + col + 2] = u1;
  }
  __syncthreads();
  for (int idx = t; idx < 64 * 64; idx += 256) {
    int l = idx >> 6, c = idx & 63;
    xn[((size_t)b * LSEQ + l0 + l) * NDIM + c0 + c] = tile[c * 66 + l];
  }
}

// ---------------- K2a: 128x128 GEMM, global_load_lds staging (m97 pattern) ----
template <typename OT>
__global__ __launch_bounds__(256) void gemm128(
    const unsigned short* __restrict__ A, const unsigned short* __restrict__ W,
    OT* __restrict__ C, int K, int ldc)
{
  __shared__ short As[128 * 32];
  __shared__ short Ws[128 * 32];
  int t = threadIdx.x;
  int wave = t >> 6, lane = t & 63;
  int m0 = blockIdx.x * 128, n0 = blockIdx.y * 128;
  int wm = wave >> 1, wn = wave & 1;
  int lrow = lane & 15, quad = lane >> 4;
  int l4 = lane >> 2, p = lane & 3;
  int row0 = wave * 32 + l4;
  int row1 = row0 + 16;
  int k8 = p ^ (row0 & 3);
  int ldsoff0 = wave * 1024 + lane * 8;        // shorts
  int ldsoff1 = ldsoff0 + 512;
  int swz = (lrow & 3) * 8;
  v4f acc[4][4];
  #pragma unroll
  for (int i = 0; i < 4; i++)
    #pragma unroll
    for (int j = 0; j < 4; j++) acc[i][j] = (v4f){0.f, 0.f, 0.f, 0.f};
  for (int kk = 0; kk < K; kk += 32) {
    gl2lds16(A + (size_t)(m0 + row0) * K + kk + k8 * 8, &As[ldsoff0]);
    gl2lds16(A + (size_t)(m0 + row1) * K + kk + k8 * 8, &As[ldsoff1]);
    gl2lds16(W + (size_t)(n0 + row0) * K + kk + k8 * 8, &Ws[ldsoff0]);
    gl2lds16(W + (size_t)(n0 + row1) * K + kk + k8 * 8, &Ws[ldsoff1]);
    __syncthreads();
    v8s af[4], bf[4];
    #pragma unroll
    for (int i = 0; i < 4; i++) {
      int ra = wm * 64 + i * 16 + lrow;
      af[i] = *(const v8s*)&As[ra * 32 + ((quad * 8) ^ swz)];
    }
    #pragma unroll
    for (int j = 0; j < 4; j++) {
      int rb = wn * 64 + j * 16 + lrow;
      bf[j] = *(const v8s*)&Ws[rb * 32 + ((quad * 8) ^ swz)];
    }
    #pragma unroll
    for (int i = 0; i < 4; i++)
      #pragma unroll
      for (int j = 0; j < 4; j++)
        acc[i][j] = __builtin_amdgcn_mfma_f32_16x16x32_bf16(af[i], bf[j], acc[i][j], 0, 0, 0);
    __syncthreads();
  }
  #pragma unroll
  for (int i = 0; i < 4; i++) {
    #pragma unroll
    for (int j = 0; j < 4; j++) {
      #pragma unroll
      for (int r = 0; r < 4; r++) {
        int m = m0 + wm * 64 + i * 16 + quad * 4 + r;
        int n = n0 + wn * 64 + j * 16 + lrow;
        if constexpr (sizeof(OT) == 4) C[(size_t)m * ldc + n] = acc[i][j][r];
        else                           C[(size_t)m * ldc + n] = (OT)f2b(acc[i][j][r]);
      }
    }
  }
}

// ---------------- K2a': out_proj fused with transpose -------------------------
// C[m][n] = sum_k Wout[m][k] * Y[n][k]; m = channel (384), n = token (16384).
// Store directly to out[(b*NDIM + m)*LSEQ + l], n = b*LSEQ + l (lanes vary l).
__global__ __launch_bounds__(256) void gemm_out(
    const unsigned short* __restrict__ A, const unsigned short* __restrict__ W,
    float* __restrict__ out, int K)
{
  __shared__ short As[128 * 32];
  __shared__ short Ws[128 * 32];
  int t = threadIdx.x;
  int wave = t >> 6, lane = t & 63;
  int m0 = blockIdx.x * 128, n0 = blockIdx.y * 128;
  int wm = wave >> 1, wn = wave & 1;
  int lrow = lane & 15, quad = lane >> 4;
  int l4 = lane >> 2, p = lane & 3;
  int row0 = wave * 32 + l4;
  int row1 = row0 + 16;
  int k8 = p ^ (row0 & 3);
  int ldsoff0 = wave * 1024 + lane * 8;
  int ldsoff1 = ldsoff0 + 512;
  int swz = (lrow & 3) * 8;
  v4f acc[4][4];
  #pragma unroll
  for (int i = 0; i < 4; i++)
    #pragma unroll
    for (int j = 0; j < 4; j++) acc[i][j] = (v4f){0.f, 0.f, 0.f, 0.f};
  for (int kk = 0; kk < K; kk += 32) {
    gl2lds16(A + (size_t)(m0 + row0) * K + kk + k8 * 8, &As[ldsoff0]);
    gl2lds16(A + (size_t)(m0 + row1) * K + kk + k8 * 8, &As[ldsoff1]);
    gl2lds16(W + (size_t)(n0 + row0) * K + kk + k8 * 8, &Ws[ldsoff0]);
    gl2lds16(W + (size_t)(n0 + row1) * K + kk + k8 * 8, &Ws[ldsoff1]);
    __syncthreads();
    v8s af[4], bf[4];
    #pragma unroll
    for (int i = 0; i < 4; i++) {
      int ra = wm * 64 + i * 16 + lrow;
      af[i] = *(const v8s*)&As[ra * 32 + ((quad * 8) ^ swz)];
    }
    #pragma unroll
    for (int j = 0; j < 4; j++) {
      int rb = wn * 64 + j * 16 + lrow;
      bf[j] = *(const v8s*)&Ws[rb * 32 + ((quad * 8) ^ swz)];
    }
    #pragma unroll
    for (int i = 0; i < 4; i++)
      #pragma unroll
      for (int j = 0; j < 4; j++)
        acc[i][j] = __builtin_amdgcn_mfma_f32_16x16x32_bf16(af[i], bf[j], acc[i][j], 0, 0, 0);
    __syncthreads();
  }
  #pragma unroll
  for (int i = 0; i < 4; i++) {
    #pragma unroll
    for (int j = 0; j < 4; j++) {
      #pragma unroll
      for (int r = 0; r < 4; r++) {
        int m = m0 + wm * 64 + i * 16 + quad * 4 + r;   // channel
        int n = n0 + wn * 64 + j * 16 + lrow;           // token
        int b = n >> 12, l = n & (LSEQ - 1);
        out[((size_t)b * NDIM + m) * LSEQ + l] = acc[i][j][r];
      }
    }
  }
}

// ---------------- K2b: 64x64 GEMM (for x_proj, N=56 padded to 64) -------------
#define LDK 40
__global__ __launch_bounds__(256) void gemm_bt64(
    const unsigned short* __restrict__ A, const unsigned short* __restrict__ W,
    unsigned short* __restrict__ C, int Nw, int K, int ldc)
{
  __shared__ short As[64 * LDK];
  __shared__ short Ws[64 * LDK];
  int m0 = blockIdx.x * 64, n0 = blockIdx.y * 64;
  int t = threadIdx.x;
  int wave = t >> 6, lane = t & 63;
  int lrow = lane & 15, quad = lane >> 4;
  int ldrow = t >> 2, ldcg = t & 3;
  v4f acc[4];
  #pragma unroll
  for (int j = 0; j < 4; j++) acc[j] = (v4f){0.f, 0.f, 0.f, 0.f};
  for (int kk = 0; kk < K; kk += 32) {
    v8s av = *(const v8s*)(A + (size_t)(m0 + ldrow) * K + kk + ldcg * 8);
    *(v8s*)&As[ldrow * LDK + ldcg * 8] = av;
    int wrow = n0 + ldrow;
    v8s wv = {0, 0, 0, 0, 0, 0, 0, 0};
    if (wrow < Nw) wv = *(const v8s*)(W + (size_t)wrow * K + kk + ldcg * 8);
    *(v8s*)&Ws[ldrow * LDK + ldcg * 8] = wv;
    __syncthreads();
    v8s afrag = *(const v8s*)&As[(wave * 16 + lrow) * LDK + quad * 8];
    #pragma unroll
    for (int j = 0; j < 4; j++) {
      v8s bfrag = *(const v8s*)&Ws[(j * 16 + lrow) * LDK + quad * 8];
      acc[j] = __builtin_amdgcn_mfma_f32_16x16x32_bf16(afrag, bfrag, acc[j], 0, 0, 0);
    }
    __syncthreads();
  }
  #pragma unroll
  for (int j = 0; j < 4; j++) {
    #pragma unroll
    for (int r = 0; r < 4; r++) {
      int m = m0 + wave * 16 + quad * 4 + r;
      int n = n0 + j * 16 + lrow;
      if (n < ldc) C[(size_t)m * ldc + n] = f2b(acc[j][r]);
    }
  }
}

// ---------------- K2c: dt GEMM: delta = softplus(dbl[:, :24] @ Wdt_pad^T + b) -
__global__ __launch_bounds__(256) void dt_gemm(
    const unsigned short* __restrict__ A, const unsigned short* __restrict__ W,
    const float* __restrict__ b_dt, unsigned short* __restrict__ delta)
{
  __shared__ short As[128 * 32];
  __shared__ short Ws[128 * 32];
  int t = threadIdx.x;
  int wave = t >> 6, lane = t & 63;
  int m0 = blockIdx.x * 128, n0 = blockIdx.y * 128;
  int wm = wave >> 1, wn = wave & 1;
  int lrow = lane & 15, quad = lane >> 4;
  int l4 = lane >> 2, p = lane & 3;
  int row0 = wave * 32 + l4;
  int row1 = row0 + 16;
  int k8 = p ^ (row0 & 3);
  int ldsoff0 = wave * 1024 + lane * 8;
  int ldsoff1 = ldsoff0 + 512;
  int swz = (lrow & 3) * 8;
  gl2lds16(A + (size_t)(m0 + row0) * 64 + k8 * 8, &As[ldsoff0]);
  gl2lds16(A + (size_t)(m0 + row1) * 64 + k8 * 8, &As[ldsoff1]);
  gl2lds16(W + (size_t)(n0 + row0) * 32 + k8 * 8, &Ws[ldsoff0]);
  gl2lds16(W + (size_t)(n0 + row1) * 32 + k8 * 8, &Ws[ldsoff1]);
  __syncthreads();
  v4f acc[4][4];
  #pragma unroll
  for (int i = 0; i < 4; i++)
    #pragma unroll
    for (int j = 0; j < 4; j++) acc[i][j] = (v4f){0.f, 0.f, 0.f, 0.f};
  v8s af[4], bf[4];
  #pragma unroll
  for (int i = 0; i < 4; i++) {
    int ra = wm * 64 + i * 16 + lrow;
    af[i] = *(const v8s*)&As[ra * 32 + ((quad * 8) ^ swz)];
  }
  #pragma unroll
  for (int j = 0; j < 4; j++) {
    int rb = wn * 64 + j * 16 + lrow;
    bf[j] = *(const v8s*)&Ws[rb * 32 + ((quad * 8) ^ swz)];
  }
  #pragma unroll
  for (int i = 0; i < 4; i++)
    #pragma unroll
    for (int j = 0; j < 4; j++)
      acc[i][j] = __builtin_amdgcn_mfma_f32_16x16x32_bf16(af[i], bf[j], acc[i][j], 0, 0, 0);
  #pragma unroll
  for (int j = 0; j < 4; j++) {
    int n = n0 + wn * 64 + j * 16 + lrow;
    float bb = b_dt[n];
    #pragma unroll
    for (int i = 0; i < 4; i++) {
      #pragma unroll
      for (int r = 0; r < 4; r++) {
        int m = m0 + wm * 64 + i * 16 + quad * 4 + r;
        float a = acc[i][j][r] + bb;
        float sp = (a > 20.f) ? a : __logf(1.f + __expf(a));
        delta[(size_t)m * DIN + n] = f2b(sp);
      }
    }
  }
}

// ---------------- K3: causal depthwise conv (k=4) + SiLU, register window -----
__global__ __launch_bounds__(256) void conv_silu_w(
    const unsigned short* __restrict__ xz, const float* __restrict__ conv_w,
    const float* __restrict__ conv_b, unsigned short* __restrict__ xc)
{
  int idx = blockIdx.x * 256 + threadIdx.x;
  int dg = idx % (DIN / 8);
  int bl0 = idx / (DIN / 8);
  int d = dg * 8;
  int t0 = bl0 * CT;                 // global token
  int l0 = t0 & (LSEQ - 1);          // within-batch position
  float w[4][8], bb[8];
  #pragma unroll
  for (int e = 0; e < 8; e++) {
    float4 we = *(const float4*)(conv_w + (size_t)(d + e) * 4);
    w[0][e] = we.x; w[1][e] = we.y; w[2][e] = we.z; w[3][e] = we.w;
  }
  {
    float4 b0 = *(const float4*)(conv_b + d);
    float4 b1 = *(const float4*)(conv_b + d + 4);
    bb[0] = b0.x; bb[1] = b0.y; bb[2] = b0.z; bb[3] = b0.w;
    bb[4] = b1.x; bb[5] = b1.y; bb[6] = b1.z; bb[7] = b1.w;
  }
  float xw[3][8];                    // x[t-3], x[t-2], x[t-1]
  #pragma unroll
  for (int j = 0; j < 3; j++) {
    if (l0 - 3 + j >= 0) {
      v8s v = *(const v8s*)(xz + (size_t)(t0 - 3 + j) * (2 * DIN) + d);
      #pragma unroll
      for (int e = 0; e < 8; e++) xw[j][e] = b2f((unsigned short)v[e]);
    } else {
      #pragma unroll
      for (int e = 0; e < 8; e++) xw[j][e] = 0.f;
    }
  }
  for (int tt = 0; tt < CT; tt++) {
    v8s v = *(const v8s*)(xz + (size_t)(t0 + tt) * (2 * DIN) + d);
    float cur[8];
    #pragma unroll
    for (int e = 0; e < 8; e++) cur[e] = b2f((unsigned short)v[e]);
    v8s o;
    #pragma unroll
    for (int e = 0; e < 8; e++) {
      float acc = bb[e];
      acc = __builtin_fmaf(w[0][e], xw[0][e], acc);
      acc = __builtin_fmaf(w[1][e], xw[1][e], acc);
      acc = __builtin_fmaf(w[2][e], xw[2][e], acc);
      acc = __builtin_fmaf(w[3][e], cur[e], acc);
      float sig = 1.f / (1.f + __expf(-acc));
      o[e] = (short)f2b(acc * sig);
    }
    *(v8s*)(xc + (size_t)(t0 + tt) * DIN + d) = o;
    #pragma unroll
    for (int e = 0; e < 8; e++) {
      xw[0][e] = xw[1][e]; xw[1][e] = xw[2][e]; xw[2][e] = cur[e];
    }
  }
}

// ---------------- K6: scan pass A: 2 d-channels per thread, 128-thread blocks -
// grid B*NCHUNK*3; thread t handles d0 = q*256+2t, d1 = d0+1.
__global__ __launch_bounds__(128) void scan_a(
    const unsigned short* __restrict__ delta, const unsigned short* __restrict__ xc,
    const unsigned short* __restrict__ dbl, const float* __restrict__ A_log,
    float* __restrict__ P, float* __restrict__ H)
{
  __shared__ float BCf[CLEN * 32];
  int blk = blockIdx.x;
  int q = blk % 3, c = (blk / 3) % NCHUNK, b = blk / (3 * NCHUNK);
  int t = threadIdx.x;
  int d0 = q * 256 + 2 * t, d1 = d0 + 1;
  {
    int tt = t >> 2, g = t & 3;
    v8s raw = *(const v8s*)(dbl + (size_t)(b * LSEQ + c * CLEN + tt) * 64 + DTR + g * 8);
    float* dst = &BCf[tt * 32 + g * 8];
    #pragma unroll
    for (int e = 0; e < 8; e++) dst[e] = b2f((unsigned short)raw[e]);
  }
  __syncthreads();
  bool fast = true;
  #pragma unroll
  for (int s = 0; s < DST; s++) {
    float a0 = __expf(A_log[d0 * DST + s]);
    float a1 = __expf(A_log[d1 * DST + s]);
    fast = fast && (__builtin_fabsf(a0 - (float)(s + 1)) < 1e-3f * (s + 1))
                && (__builtin_fabsf(a1 - (float)(s + 1)) < 1e-3f * (s + 1));
  }
  float h0[DST], h1[DST];
  #pragma unroll
  for (int s = 0; s < DST; s++) { h0[s] = 0.f; h1[s] = 0.f; }
  float S0 = 0.f, S1 = 0.f;
  size_t base = ((size_t)b * LSEQ + c * CLEN) * DIN + d0;
  size_t obase = (((size_t)b * NCHUNK + c) * DST) * DIN + d0;
  if (fast) {
    for (int tt = 0; tt < CLEN; tt++) {
      unsigned int wd = *(const unsigned int*)(delta + base + (size_t)tt * DIN);
      unsigned int wx = *(const unsigned int*)(xc + base + (size_t)tt * DIN);
      float du0 = blo(wd), du1 = bhi(wd);
      float x0 = blo(wx), x1 = bhi(wx);
      S0 += du0; S1 += du1;
      float r0 = __expf(-du0), r1 = __expf(-du1);
      float dx0 = du0 * x0, dx1 = du1 * x1;
      float Bv[16];
      #pragma unroll
      for (int g = 0; g < 4; g++)
        *(float4*)&Bv[g * 4] = *(const float4*)&BCf[tt * 32 + g * 4];
      float a0 = r0, a1 = r1;
      #pragma unroll
      for (int s = 0; s < DST; s++) {
        h0[s] = __builtin_fmaf(h0[s], a0, dx0 * Bv[s]);
        h1[s] = __builtin_fmaf(h1[s], a1, dx1 * Bv[s]);
        a0 *= r0; a1 *= r1;
      }
    }
    float rS0 = __expf(-S0), rS1 = __expf(-S1);
    float a0 = rS0, a1 = rS1;
    #pragma unroll
    for (int s = 0; s < DST; s++) {
      *(float2*)&P[obase + (size_t)s * DIN] = (float2){a0, a1};
      a0 *= rS0; a1 *= rS1;
    }
  } else {
    float A0[DST], A1[DST];
    #pragma unroll
    for (int s = 0; s < DST; s++) {
      A0[s] = -__expf(A_log[d0 * DST + s]);
      A1[s] = -__expf(A_log[d1 * DST + s]);
    }
    for (int tt = 0; tt < CLEN; tt++) {
      unsigned int wd = *(const unsigned int*)(delta + base + (size_t)tt * DIN);
      unsigned int wx = *(const unsigned int*)(xc + base + (size_t)tt * DIN);
      float du0 = blo(wd), du1 = bhi(wd);
      float x0 = blo(wx), x1 = bhi(wx);
      S0 += du0; S1 += du1;
      float dx0 = du0 * x0, dx1 = du1 * x1;
      #pragma unroll
      for (int s = 0; s < DST; s++) {
        float Bs = BCf[tt * 32 + s];
        h0[s] = h0[s] * __expf(du0 * A0[s]) + dx0 * Bs;
        h1[s] = h1[s] * __expf(du1 * A1[s]) + dx1 * Bs;
      }
    }
    #pragma unroll
    for (int s = 0; s < DST; s++)
      *(float2*)&P[obase + (size_t)s * DIN] = (float2){__expf(A0[s] * S0), __expf(A1[s] * S1)};
  }
  #pragma unroll
  for (int s = 0; s < DST; s++)
    *(float2*)&H[obase + (size_t)s * DIN] = (float2){h0[s], h1[s]};
}

// ---------------- K7: scan pass B: sequential cross-chunk combine -------------
// NOTE: Hstart aliases P (read P/H before writing Hstart).
__global__ __launch_bounds__(256) void scan_b(
    const float* __restrict__ P, const float* __restrict__ H, float* __restrict__ Hstart)
{
  int i = blockIdx.x * 256 + threadIdx.x;
  if (i >= BATCH * DST * DIN) return;
  int d = i % DIN;
  int s = (i / DIN) % DST;
  int b = i / (DST * DIN);
  float h = 0.f;
  for (int c = 0; c < NCHUNK; c++) {
    size_t idx = (((size_t)b * NCHUNK + c) * DST + s) * DIN + d;
    float p = P[idx];
    float hh = H[idx];
    Hstart[idx] = h;
    h = h * p + hh;
  }
}

// ---------------- K8: scan pass C: final scan + y + skip + gate (2 d/thread) --
__global__ __launch_bounds__(128) void scan_c(
    const unsigned short* __restrict__ delta, const unsigned short* __restrict__ xc,
    const unsigned short* __restrict__ dbl, const float* __restrict__ A_log,
    const float* __restrict__ Hstart, const unsigned short* __restrict__ xz,
    const float* __restrict__ Dp, unsigned short* __restrict__ ygate)
{
  __shared__ float BCf[CLEN * 32];
  int blk = blockIdx.x;
  int q = blk % 3, c = (blk / 3) % NCHUNK, b = blk / (3 * NCHUNK);
  int t = threadIdx.x;
  int d0 = q * 256 + 2 * t, d1 = d0 + 1;
  {
    int tt = t >> 2, g = t & 3;
    v8s raw = *(const v8s*)(dbl + (size_t)(b * LSEQ + c * CLEN + tt) * 64 + DTR + g * 8);
    float* dst = &BCf[tt * 32 + g * 8];
    #pragma unroll
    for (int e = 0; e < 8; e++) dst[e] = b2f((unsigned short)raw[e]);
  }
  __syncthreads();
  bool fast = true;
  #pragma unroll
  for (int s = 0; s < DST; s++) {
    float a0 = __expf(A_log[d0 * DST + s]);
    float a1 = __expf(A_log[d1 * DST + s]);
    fast = fast && (__builtin_fabsf(a0 - (float)(s + 1)) < 1e-3f * (s + 1))
                && (__builtin_fabsf(a1 - (float)(s + 1)) < 1e-3f * (s + 1));
  }
  size_t obase = (((size_t)b * NCHUNK + c) * DST) * DIN + d0;
  float h0[DST], h1[DST];
  #pragma unroll
  for (int s = 0; s < DST; s++) {
    float2 hs = *(const float2*)&Hstart[obase + (size_t)s * DIN];
    h0[s] = hs.x; h1[s] = hs.y;
  }
  float Dv0 = Dp[d0], Dv1 = Dp[d1];
  size_t base = ((size_t)b * LSEQ + c * CLEN) * DIN + d0;
  size_t zbase = ((size_t)b * LSEQ + c * CLEN) * (2 * DIN) + DIN + d0;
  if (fast) {
    for (int tt = 0; tt < CLEN; tt++) {
      unsigned int wd = *(const unsigned int*)(delta + base + (size_t)tt * DIN);
      unsigned int wx = *(const unsigned int*)(xc + base + (size_t)tt * DIN);
      float du0 = blo(wd), du1 = bhi(wd);
      float x0 = blo(wx), x1 = bhi(wx);
      float dx0 = du0 * x0, dx1 = du1 * x1;
      float r0 = __expf(-du0), r1 = __expf(-du1);
      float Bv[16], Cv[16];
      #pragma unroll
      for (int g = 0; g < 4; g++) {
        *(float4*)&Bv[g * 4] = *(const float4*)&BCf[tt * 32 + g * 4];
        *(float4*)&Cv[g * 4] = *(const float4*)&BCf[tt * 32 + 16 + g * 4];
      }
      float a0 = r0, a1 = r1, y0 = 0.f, y1 = 0.f;
      #pragma unroll
      for (int s = 0; s < DST; s++) {
        h0[s] = __builtin_fmaf(h0[s], a0, dx0 * Bv[s]);
        h1[s] = __builtin_fmaf(h1[s], a1, dx1 * Bv[s]);
        y0 = __builtin_fmaf(h0[s], Cv[s], y0);
        y1 = __builtin_fmaf(h1[s], Cv[s], y1);
        a0 *= r0; a1 *= r1;
      }
      unsigned int wz = *(const unsigned int*)(xz + zbase + (size_t)tt * (2 * DIN));
      float z0 = blo(wz), z1 = bhi(wz);
      float g0 = z0 / (1.f + __expf(-z0));
      float g1 = z1 / (1.f + __expf(-z1));
      float o0 = (y0 + x0 * Dv0) * g0;
      float o1 = (y1 + x1 * Dv1) * g1;
      unsigned int ow = (unsigned int)f2b(o0) | ((unsigned int)f2b(o1) << 16);
      *(unsigned int*)(ygate + base + (size_t)tt * DIN) = ow;
    }
  } else {
    float A0[DST], A1[DST];
    #pragma unroll
    for (int s = 0; s < DST; s++) {
      A0[s] = -__expf(A_log[d0 * DST + s]);
      A1[s] = -__expf(A_log[d1 * DST + s]);
    }
    for (int tt = 0; tt < CLEN; tt++) {
      unsigned int wd = *(const unsigned int*)(delta + base + (size_t)tt * DIN);
      unsigned int wx = *(const unsigned int*)(xc + base + (size_t)tt * DIN);
      float du0 = blo(wd), du1 = bhi(wd);
      float x0 = blo(wx), x1 = bhi(wx);
      float dx0 = du0 * x0, dx1 = du1 * x1;
      float y0 = 0.f, y1 = 0.f;
      #pragma unroll
      for (int s = 0; s < DST; s++) {
        float Bs = BCf[tt * 32 + s], Cs = BCf[tt * 32 + 16 + s];
        h0[s] = h0[s] * __expf(du0 * A0[s]) + dx0 * Bs;
        h1[s] = h1[s] * __expf(du1 * A1[s]) + dx1 * Bs;
        y0 += h0[s] * Cs;
        y1 += h1[s] * Cs;
      }
      unsigned int wz = *(const unsigned int*)(xz + zbase + (size_t)tt * (2 * DIN));
      float z0 = blo(wz), z1 = bhi(wz);
      float g0 = z0 / (1.f + __expf(-z0));
      float g1 = z1 / (1.f + __expf(-z1));
      float o0 = (y0 + x0 * Dv0) * g0;
      float o1 = (y1 + x1 * Dv1) * g1;
      unsigned int ow = (unsigned int)f2b(o0) | ((unsigned int)f2b(o1) << 16);
      *(unsigned int*)(ygate + base + (size_t)tt * DIN) = ow;
    }
  }
}

extern "C" void kernel_launch(void* const* d_in, const int* in_sizes, int n_in,
                              void* d_out, int out_size, void* d_ws, size_t ws_size,
                              hipStream_t stream) {
  const float* x      = (const float*)d_in[0];
  const float* gamma  = (const float*)d_in[1];
  const float* beta   = (const float*)d_in[2];
  const float* W_in   = (const float*)d_in[3];
  const float* conv_w = (const float*)d_in[4];
  const float* conv_b = (const float*)d_in[5];
  const float* W_xprj = (const float*)d_in[6];
  const float* W_dt   = (const float*)d_in[7];
  const float* b_dt   = (const float*)d_in[8];
  const float* A_log  = (const float*)d_in[9];
  const float* Dp     = (const float*)d_in[10];
  const float* W_out  = (const float*)d_in[11];
  float* out = (float*)d_out;

  char* ws = (char*)d_ws;
  size_t off = 0;
  auto take = [&](size_t bytes) -> char* {
    char* p = ws + off;
    off = (off + bytes + 255) & ~(size_t)255;
    return p;
  };
  const int NW_IN = 2 * DIN * NDIM;      // 589824
  const int NW_XP = 56 * DIN;            // 43008
  const int NW_OUT = NDIM * DIN;         // 294912
  unsigned short* Wc_in  = (unsigned short*)take((size_t)NW_IN * 2);
  unsigned short* Wc_xp  = (unsigned short*)take((size_t)NW_XP * 2);
  unsigned short* Wc_out = (unsigned short*)take((size_t)NW_OUT * 2);
  unsigned short* Wc_dt  = (unsigned short*)take((size_t)DIN * 32 * 2);
  float*          mu    = (float*)take((size_t)NTOK * 4);
  float*          rsb   = (float*)take((size_t)NTOK * 4);
  unsigned short* xn    = (unsigned short*)take((size_t)NTOK * NDIM * 2);      // 12.6 MB
  unsigned short* xz    = (unsigned short*)take((size_t)NTOK * 2 * DIN * 2);   // 50.3 MB
  unsigned short* xc    = (unsigned short*)take((size_t)NTOK * DIN * 2);       // 25.2 MB
  unsigned short* dbl   = (unsigned short*)take((size_t)NTOK * 64 * 2);        //  2.1 MB
  unsigned short* delta = (unsigned short*)take((size_t)NTOK * DIN * 2);       // 25.2 MB
  unsigned short* ygate = (unsigned short*)take((size_t)NTOK * DIN * 2);       // 25.2 MB
  float*          P     = (float*)take((size_t)BATCH * NCHUNK * DST * DIN * 4);// 25.2 MB
  float*          H     = (float*)take((size_t)BATCH * NCHUNK * DST * DIN * 4);// 25.2 MB
  float*          Hst   = P;                       // alias (scan_b reads-then-writes)
  (void)ws_size; (void)in_sizes; (void)n_in; (void)out_size;

  // 0. cast weights to bf16 (+ W_dt pad to K=32)
  cast_w<<<(NW_IN + 255) / 256, 256, 0, stream>>>(W_in, Wc_in, NW_IN,
                                                  W_xprj, Wc_xp, NW_XP,
                                                  W_out, Wc_out, NW_OUT,
                                                  W_dt, Wc_dt);
  // 1. LayerNorm (stats, then apply+transpose)
  ln_stats<<<BATCH * (LSEQ / 32), 256, 0, stream>>>(x, mu, rsb);
  ln_apply<<<BATCH * 6 * (LSEQ / 64), 256, 0, stream>>>(x, mu, rsb, gamma, beta, xn);
  // 2. in_proj: (16384,384) x (1536,384)^T -> xz bf16
  gemm128<unsigned short><<<dim3(NTOK / 128, 1536 / 128), 256, 0, stream>>>(xn, Wc_in, xz, NDIM, 1536);
  // 3. causal conv + SiLU -> xc bf16 (register-window, CT tokens/thread)
  conv_silu_w<<<(NTOK / CT) * (DIN / 8) / 256, 256, 0, stream>>>(xz, conv_w, conv_b, xc);
  // 4. x_proj: (16384,768) x (56,768)^T -> dbl bf16 [cols 56..63 zero]
  gemm_bt64<<<dim3(NTOK / 64, 1), 256, 0, stream>>>(xc, Wc_xp, dbl, 56, DIN, 64);
  // 5. dt_proj as MFMA GEMM + fused softplus -> delta bf16
  dt_gemm<<<dim3(NTOK / 128, DIN / 128), 256, 0, stream>>>(dbl, Wc_dt, b_dt, delta);
  // 6-8. chunked selective scan (CLEN=32, NCHUNK=128, 2 d/thread)
  scan_a<<<BATCH * NCHUNK * 3, 128, 0, stream>>>(delta, xc, dbl, A_log, P, H);
  scan_b<<<(BATCH * DST * DIN + 255) / 256, 256, 0, stream>>>(P, H, Hst);
  scan_c<<<BATCH * NCHUNK * 3, 128, 0, stream>>>(delta, xc, dbl, A_log, Hst, xz, Dp, ygate);
  // 9. out_proj fused with output transpose: out[(b*384+c)*4096+l]
  gemm_out<<<dim3(NDIM / 128, NTOK / 128), 256, 0, stream>>>(Wc_out, ygate, out, DIN);
}

// Round 8
// 308.641 us; speedup vs baseline: 1.1667x; 1.1667x over previous
//
#include <hip/hip_runtime.h>

typedef short v8s __attribute__((ext_vector_type(8)));
typedef float v4f __attribute__((ext_vector_type(4)));

#define LSEQ   4096
#define BATCH  4
#define NDIM   384
#define DIN    768
#define DST    16
#define DTR    24
#define NTOK   (BATCH * LSEQ)   // 16384
#define NCHUNK 128
#define CLEN   32
#define CT     8                // tokens per thread in conv

__device__ __forceinline__ float b2f(unsigned short u) {
  unsigned int v = ((unsigned int)u) << 16;
  float f; __builtin_memcpy(&f, &v, 4); return f;
}
__device__ __forceinline__ unsigned short f2b(float f) {
  unsigned int x; __builtin_memcpy(&x, &f, 4);
  unsigned int r = x + 0x7FFFu + ((x >> 16) & 1u);
  return (unsigned short)(r >> 16);
}
__device__ __forceinline__ void gl2lds16(const void* g, void* l) {
  __builtin_amdgcn_global_load_lds(
      (const __attribute__((address_space(1))) void*)g,
      (__attribute__((address_space(3))) void*)l, 16, 0, 0);
}

// ---------------- K0: cast GEMM weights f32 -> bf16 (+ W_dt zero-pad 24->32) --
__global__ __launch_bounds__(256) void cast_w(
    const float* __restrict__ a, unsigned short* __restrict__ oa, int na,
    const float* __restrict__ b, unsigned short* __restrict__ ob, int nb,
    const float* __restrict__ c, unsigned short* __restrict__ oc, int nc,
    const float* __restrict__ wdt, unsigned short* __restrict__ odt)
{
  int i = blockIdx.x * 256 + threadIdx.x;
  if (i < na) oa[i] = f2b(a[i]);
  if (i < nb) ob[i] = f2b(b[i]);
  if (i < nc) oc[i] = f2b(c[i]);
  if (i < DIN * 32) {
    int n = i >> 5, r = i & 31;
    odt[i] = (r < DTR) ? f2b(wdt[n * DTR + r]) : (unsigned short)0;
  }
}

// ---------------- K1a: LN stats: mu, rs per token -----------------------------
__global__ __launch_bounds__(256) void ln_stats(
    const float* __restrict__ x, float* __restrict__ mu, float* __restrict__ rs)
{
  __shared__ float red[512];
  int blk = blockIdx.x;
  int b = blk >> 7, lc = blk & 127;
  int l0 = lc * 32;
  int t = threadIdx.x;
  int lt = t & 31, part = t >> 5;   // 8 parts, 48 channels each
  float s = 0.f, ss = 0.f;
  for (int c = part; c < NDIM; c += 8) {
    float v = x[((size_t)b * NDIM + c) * LSEQ + l0 + lt];
    s += v; ss += v * v;
  }
  red[part * 32 + lt] = s;
  red[256 + part * 32 + lt] = ss;
  __syncthreads();
  if (t < 32) {
    float sum = 0.f, ssum = 0.f;
    #pragma unroll
    for (int k = 0; k < 8; k++) { sum += red[k * 32 + t]; ssum += red[256 + k * 32 + t]; }
    float m = sum / (float)NDIM;
    float var = ssum / (float)NDIM - m * m;
    mu[(size_t)b * LSEQ + l0 + t] = m;
    rs[(size_t)b * LSEQ + l0 + t] = rsqrtf(var + 1e-5f);
  }
}

// ---------------- K1b: LN apply + transpose: (B,C,L) f32 -> (B*L,C) bf16 ------
__global__ __launch_bounds__(256) void ln_apply(
    const float* __restrict__ x, const float* __restrict__ mu,
    const float* __restrict__ rs, const float* __restrict__ gamma,
    const float* __restrict__ beta, unsigned short* __restrict__ xn)
{
  __shared__ unsigned short tile[64 * 66];
  int blk = blockIdx.x;
  int ltb = blk & 63, ct = (blk >> 6) % 6, b = blk / (6 * 64);
  int l0 = ltb * 64, c0 = ct * 64;
  int t = threadIdx.x;
  int col = (t & 15) * 4;
  float4 mu4 = *(const float4*)(mu + (size_t)b * LSEQ + l0 + col);
  float4 rs4 = *(const float4*)(rs + (size_t)b * LSEQ + l0 + col);
  #pragma unroll
  for (int p = 0; p < 4; p++) {
    int row = (t >> 4) + p * 16;
    float g = gamma[c0 + row], be = beta[c0 + row];
    float4 v = *(const float4*)(x + ((size_t)b * NDIM + c0 + row) * LSEQ + l0 + col);
    unsigned int u0 = (unsigned int)f2b((v.x - mu4.x) * rs4.x * g + be)
                    | ((unsigned int)f2b((v.y - mu4.y) * rs4.y * g + be) << 16);
    unsigned int u1 = (unsigned int)f2b((v.z - mu4.z) * rs4.z * g + be)
                    | ((unsigned int)f2b((v.w - mu4.w) * rs4.w * g + be) << 16);
    *(unsigned int*)&tile[row * 66 + col]     = u0;
    *(unsigned int*)&tile[row * 66 + col + 2] = u1;
  }
  __syncthreads();
  for (int idx = t; idx < 64 * 64; idx += 256) {
    int l = idx >> 6, c = idx & 63;
    xn[((size_t)b * LSEQ + l0 + l) * NDIM + c0 + c] = tile[c * 66 + l];
  }
}

// ---------------- K2a: 128x128 GEMM, global_load_lds staging (m97 pattern) ----
template <typename OT>
__global__ __launch_bounds__(256) void gemm128(
    const unsigned short* __restrict__ A, const unsigned short* __restrict__ W,
    OT* __restrict__ C, int K, int ldc)
{
  __shared__ short As[128 * 32];
  __shared__ short Ws[128 * 32];
  int t = threadIdx.x;
  int wave = t >> 6, lane = t & 63;
  int m0 = blockIdx.x * 128, n0 = blockIdx.y * 128;
  int wm = wave >> 1, wn = wave & 1;
  int lrow = lane & 15, quad = lane >> 4;
  int l4 = lane >> 2, p = lane & 3;
  int row0 = wave * 32 + l4;
  int row1 = row0 + 16;
  int k8 = p ^ (row0 & 3);
  int ldsoff0 = wave * 1024 + lane * 8;        // shorts
  int ldsoff1 = ldsoff0 + 512;
  int swz = (lrow & 3) * 8;
  v4f acc[4][4];
  #pragma unroll
  for (int i = 0; i < 4; i++)
    #pragma unroll
    for (int j = 0; j < 4; j++) acc[i][j] = (v4f){0.f, 0.f, 0.f, 0.f};
  for (int kk = 0; kk < K; kk += 32) {
    gl2lds16(A + (size_t)(m0 + row0) * K + kk + k8 * 8, &As[ldsoff0]);
    gl2lds16(A + (size_t)(m0 + row1) * K + kk + k8 * 8, &As[ldsoff1]);
    gl2lds16(W + (size_t)(n0 + row0) * K + kk + k8 * 8, &Ws[ldsoff0]);
    gl2lds16(W + (size_t)(n0 + row1) * K + kk + k8 * 8, &Ws[ldsoff1]);
    __syncthreads();
    v8s af[4], bf[4];
    #pragma unroll
    for (int i = 0; i < 4; i++) {
      int ra = wm * 64 + i * 16 + lrow;
      af[i] = *(const v8s*)&As[ra * 32 + ((quad * 8) ^ swz)];
    }
    #pragma unroll
    for (int j = 0; j < 4; j++) {
      int rb = wn * 64 + j * 16 + lrow;
      bf[j] = *(const v8s*)&Ws[rb * 32 + ((quad * 8) ^ swz)];
    }
    #pragma unroll
    for (int i = 0; i < 4; i++)
      #pragma unroll
      for (int j = 0; j < 4; j++)
        acc[i][j] = __builtin_amdgcn_mfma_f32_16x16x32_bf16(af[i], bf[j], acc[i][j], 0, 0, 0);
    __syncthreads();
  }
  #pragma unroll
  for (int i = 0; i < 4; i++) {
    #pragma unroll
    for (int j = 0; j < 4; j++) {
      #pragma unroll
      for (int r = 0; r < 4; r++) {
        int m = m0 + wm * 64 + i * 16 + quad * 4 + r;
        int n = n0 + wn * 64 + j * 16 + lrow;
        if constexpr (sizeof(OT) == 4) C[(size_t)m * ldc + n] = acc[i][j][r];
        else                           C[(size_t)m * ldc + n] = (OT)f2b(acc[i][j][r]);
      }
    }
  }
}

// ---------------- K2a': out_proj fused with transpose -------------------------
// C[m][n] = sum_k Wout[m][k] * Y[n][k]; m = channel (384), n = token (16384).
// Store directly to out[(b*NDIM + m)*LSEQ + l]; lanes vary l -> coalesced.
__global__ __launch_bounds__(256) void gemm_out(
    const unsigned short* __restrict__ A, const unsigned short* __restrict__ W,
    float* __restrict__ out, int K)
{
  __shared__ short As[128 * 32];
  __shared__ short Ws[128 * 32];
  int t = threadIdx.x;
  int wave = t >> 6, lane = t & 63;
  int m0 = blockIdx.x * 128, n0 = blockIdx.y * 128;
  int wm = wave >> 1, wn = wave & 1;
  int lrow = lane & 15, quad = lane >> 4;
  int l4 = lane >> 2, p = lane & 3;
  int row0 = wave * 32 + l4;
  int row1 = row0 + 16;
  int k8 = p ^ (row0 & 3);
  int ldsoff0 = wave * 1024 + lane * 8;
  int ldsoff1 = ldsoff0 + 512;
  int swz = (lrow & 3) * 8;
  v4f acc[4][4];
  #pragma unroll
  for (int i = 0; i < 4; i++)
    #pragma unroll
    for (int j = 0; j < 4; j++) acc[i][j] = (v4f){0.f, 0.f, 0.f, 0.f};
  for (int kk = 0; kk < K; kk += 32) {
    gl2lds16(A + (size_t)(m0 + row0) * K + kk + k8 * 8, &As[ldsoff0]);
    gl2lds16(A + (size_t)(m0 + row1) * K + kk + k8 * 8, &As[ldsoff1]);
    gl2lds16(W + (size_t)(n0 + row0) * K + kk + k8 * 8, &Ws[ldsoff0]);
    gl2lds16(W + (size_t)(n0 + row1) * K + kk + k8 * 8, &Ws[ldsoff1]);
    __syncthreads();
    v8s af[4], bf[4];
    #pragma unroll
    for (int i = 0; i < 4; i++) {
      int ra = wm * 64 + i * 16 + lrow;
      af[i] = *(const v8s*)&As[ra * 32 + ((quad * 8) ^ swz)];
    }
    #pragma unroll
    for (int j = 0; j < 4; j++) {
      int rb = wn * 64 + j * 16 + lrow;
      bf[j] = *(const v8s*)&Ws[rb * 32 + ((quad * 8) ^ swz)];
    }
    #pragma unroll
    for (int i = 0; i < 4; i++)
      #pragma unroll
      for (int j = 0; j < 4; j++)
        acc[i][j] = __builtin_amdgcn_mfma_f32_16x16x32_bf16(af[i], bf[j], acc[i][j], 0, 0, 0);
    __syncthreads();
  }
  #pragma unroll
  for (int i = 0; i < 4; i++) {
    #pragma unroll
    for (int j = 0; j < 4; j++) {
      #pragma unroll
      for (int r = 0; r < 4; r++) {
        int m = m0 + wm * 64 + i * 16 + quad * 4 + r;   // channel
        int n = n0 + wn * 64 + j * 16 + lrow;           // token
        int b = n >> 12, l = n & (LSEQ - 1);
        out[((size_t)b * NDIM + m) * LSEQ + l] = acc[i][j][r];
      }
    }
  }
}

// ---------------- K2b: 64x64 GEMM (for x_proj, N=56 padded to 64) -------------
#define LDK 40
__global__ __launch_bounds__(256) void gemm_bt64(
    const unsigned short* __restrict__ A, const unsigned short* __restrict__ W,
    unsigned short* __restrict__ C, int Nw, int K, int ldc)
{
  __shared__ short As[64 * LDK];
  __shared__ short Ws[64 * LDK];
  int m0 = blockIdx.x * 64, n0 = blockIdx.y * 64;
  int t = threadIdx.x;
  int wave = t >> 6, lane = t & 63;
  int lrow = lane & 15, quad = lane >> 4;
  int ldrow = t >> 2, ldcg = t & 3;
  v4f acc[4];
  #pragma unroll
  for (int j = 0; j < 4; j++) acc[j] = (v4f){0.f, 0.f, 0.f, 0.f};
  for (int kk = 0; kk < K; kk += 32) {
    v8s av = *(const v8s*)(A + (size_t)(m0 + ldrow) * K + kk + ldcg * 8);
    *(v8s*)&As[ldrow * LDK + ldcg * 8] = av;
    int wrow = n0 + ldrow;
    v8s wv = {0, 0, 0, 0, 0, 0, 0, 0};
    if (wrow < Nw) wv = *(const v8s*)(W + (size_t)wrow * K + kk + ldcg * 8);
    *(v8s*)&Ws[ldrow * LDK + ldcg * 8] = wv;
    __syncthreads();
    v8s afrag = *(const v8s*)&As[(wave * 16 + lrow) * LDK + quad * 8];
    #pragma unroll
    for (int j = 0; j < 4; j++) {
      v8s bfrag = *(const v8s*)&Ws[(j * 16 + lrow) * LDK + quad * 8];
      acc[j] = __builtin_amdgcn_mfma_f32_16x16x32_bf16(afrag, bfrag, acc[j], 0, 0, 0);
    }
    __syncthreads();
  }
  #pragma unroll
  for (int j = 0; j < 4; j++) {
    #pragma unroll
    for (int r = 0; r < 4; r++) {
      int m = m0 + wave * 16 + quad * 4 + r;
      int n = n0 + j * 16 + lrow;
      if (n < ldc) C[(size_t)m * ldc + n] = f2b(acc[j][r]);
    }
  }
}

// ---------------- K2c: dt GEMM: delta = softplus(dbl[:, :24] @ Wdt_pad^T + b) -
__global__ __launch_bounds__(256) void dt_gemm(
    const unsigned short* __restrict__ A, const unsigned short* __restrict__ W,
    const float* __restrict__ b_dt, unsigned short* __restrict__ delta)
{
  __shared__ short As[128 * 32];
  __shared__ short Ws[128 * 32];
  int t = threadIdx.x;
  int wave = t >> 6, lane = t & 63;
  int m0 = blockIdx.x * 128, n0 = blockIdx.y * 128;
  int wm = wave >> 1, wn = wave & 1;
  int lrow = lane & 15, quad = lane >> 4;
  int l4 = lane >> 2, p = lane & 3;
  int row0 = wave * 32 + l4;
  int row1 = row0 + 16;
  int k8 = p ^ (row0 & 3);
  int ldsoff0 = wave * 1024 + lane * 8;
  int ldsoff1 = ldsoff0 + 512;
  int swz = (lrow & 3) * 8;
  gl2lds16(A + (size_t)(m0 + row0) * 64 + k8 * 8, &As[ldsoff0]);
  gl2lds16(A + (size_t)(m0 + row1) * 64 + k8 * 8, &As[ldsoff1]);
  gl2lds16(W + (size_t)(n0 + row0) * 32 + k8 * 8, &Ws[ldsoff0]);
  gl2lds16(W + (size_t)(n0 + row1) * 32 + k8 * 8, &Ws[ldsoff1]);
  __syncthreads();
  v4f acc[4][4];
  #pragma unroll
  for (int i = 0; i < 4; i++)
    #pragma unroll
    for (int j = 0; j < 4; j++) acc[i][j] = (v4f){0.f, 0.f, 0.f, 0.f};
  v8s af[4], bf[4];
  #pragma unroll
  for (int i = 0; i < 4; i++) {
    int ra = wm * 64 + i * 16 + lrow;
    af[i] = *(const v8s*)&As[ra * 32 + ((quad * 8) ^ swz)];
  }
  #pragma unroll
  for (int j = 0; j < 4; j++) {
    int rb = wn * 64 + j * 16 + lrow;
    bf[j] = *(const v8s*)&Ws[rb * 32 + ((quad * 8) ^ swz)];
  }
  #pragma unroll
  for (int i = 0; i < 4; i++)
    #pragma unroll
    for (int j = 0; j < 4; j++)
      acc[i][j] = __builtin_amdgcn_mfma_f32_16x16x32_bf16(af[i], bf[j], acc[i][j], 0, 0, 0);
  #pragma unroll
  for (int j = 0; j < 4; j++) {
    int n = n0 + wn * 64 + j * 16 + lrow;
    float bb = b_dt[n];
    #pragma unroll
    for (int i = 0; i < 4; i++) {
      #pragma unroll
      for (int r = 0; r < 4; r++) {
        int m = m0 + wm * 64 + i * 16 + quad * 4 + r;
        float a = acc[i][j][r] + bb;
        float sp = (a > 20.f) ? a : __logf(1.f + __expf(a));
        delta[(size_t)m * DIN + n] = f2b(sp);
      }
    }
  }
}

// ---------------- K3: causal depthwise conv (k=4) + SiLU, register window -----
__global__ __launch_bounds__(256) void conv_silu_w(
    const unsigned short* __restrict__ xz, const float* __restrict__ conv_w,
    const float* __restrict__ conv_b, unsigned short* __restrict__ xc)
{
  int idx = blockIdx.x * 256 + threadIdx.x;
  int dg = idx % (DIN / 8);
  int bl0 = idx / (DIN / 8);
  int d = dg * 8;
  int t0 = bl0 * CT;                 // global token
  int l0 = t0 & (LSEQ - 1);          // within-batch position
  float w[4][8], bb[8];
  #pragma unroll
  for (int e = 0; e < 8; e++) {
    float4 we = *(const float4*)(conv_w + (size_t)(d + e) * 4);
    w[0][e] = we.x; w[1][e] = we.y; w[2][e] = we.z; w[3][e] = we.w;
  }
  {
    float4 b0 = *(const float4*)(conv_b + d);
    float4 b1 = *(const float4*)(conv_b + d + 4);
    bb[0] = b0.x; bb[1] = b0.y; bb[2] = b0.z; bb[3] = b0.w;
    bb[4] = b1.x; bb[5] = b1.y; bb[6] = b1.z; bb[7] = b1.w;
  }
  float xw[3][8];                    // x[t-3], x[t-2], x[t-1]
  #pragma unroll
  for (int j = 0; j < 3; j++) {
    if (l0 - 3 + j >= 0) {
      v8s v = *(const v8s*)(xz + (size_t)(t0 - 3 + j) * (2 * DIN) + d);
      #pragma unroll
      for (int e = 0; e < 8; e++) xw[j][e] = b2f((unsigned short)v[e]);
    } else {
      #pragma unroll
      for (int e = 0; e < 8; e++) xw[j][e] = 0.f;
    }
  }
  for (int tt = 0; tt < CT; tt++) {
    v8s v = *(const v8s*)(xz + (size_t)(t0 + tt) * (2 * DIN) + d);
    float cur[8];
    #pragma unroll
    for (int e = 0; e < 8; e++) cur[e] = b2f((unsigned short)v[e]);
    v8s o;
    #pragma unroll
    for (int e = 0; e < 8; e++) {
      float acc = bb[e];
      acc = __builtin_fmaf(w[0][e], xw[0][e], acc);
      acc = __builtin_fmaf(w[1][e], xw[1][e], acc);
      acc = __builtin_fmaf(w[2][e], xw[2][e], acc);
      acc = __builtin_fmaf(w[3][e], cur[e], acc);
      float sig = 1.f / (1.f + __expf(-acc));
      o[e] = (short)f2b(acc * sig);
    }
    *(v8s*)(xc + (size_t)(t0 + tt) * DIN + d) = o;
    #pragma unroll
    for (int e = 0; e < 8; e++) {
      xw[0][e] = xw[1][e]; xw[1][e] = xw[2][e]; xw[2][e] = cur[e];
    }
  }
}

// ---------------- K6: scan pass A (256thr/1ch — 24 waves/CU; see R7 note) -----
__global__ __launch_bounds__(256) void scan_a(
    const unsigned short* __restrict__ delta, const unsigned short* __restrict__ xc,
    const unsigned short* __restrict__ dbl, const float* __restrict__ A_log,
    float* __restrict__ P, float* __restrict__ H)
{
  __shared__ float BCf[CLEN * 32];
  int blk = blockIdx.x;
  int q = blk % 3, c = (blk / 3) % NCHUNK, b = blk / (3 * NCHUNK);
  int t = threadIdx.x;
  int d = q * 256 + t;
  if (t < CLEN * 4) {
    int tt = t >> 2, g = t & 3;
    v8s raw = *(const v8s*)(dbl + (size_t)(b * LSEQ + c * CLEN + tt) * 64 + DTR + g * 8);
    float* dst = &BCf[tt * 32 + g * 8];
    #pragma unroll
    for (int e = 0; e < 8; e++) dst[e] = b2f((unsigned short)raw[e]);
  }
  __syncthreads();
  float A_d[DST];
  bool fast = true;
  #pragma unroll
  for (int s = 0; s < DST; s++) {
    A_d[s] = -__expf(A_log[d * DST + s]);
    fast = fast && (__builtin_fabsf(A_d[s] + (float)(s + 1)) < 1e-3f * (s + 1));
  }
  float h[DST];
  #pragma unroll
  for (int s = 0; s < DST; s++) h[s] = 0.f;
  float S = 0.f;
  size_t base = ((size_t)b * LSEQ + c * CLEN) * DIN + d;
  if (fast) {
    for (int tt = 0; tt < CLEN; tt++) {
      float du = b2f(delta[base + (size_t)tt * DIN]);
      float xv = b2f(xc[base + (size_t)tt * DIN]);
      float dx = du * xv;
      S += du;
      float r = __expf(-du);
      float Bv[16];
      #pragma unroll
      for (int g = 0; g < 4; g++)
        *(float4*)&Bv[g * 4] = *(const float4*)&BCf[tt * 32 + g * 4];
      float a = r;
      #pragma unroll
      for (int s = 0; s < DST; s++) {
        h[s] = __builtin_fmaf(h[s], a, dx * Bv[s]);
        a *= r;
      }
    }
  } else {
    for (int tt = 0; tt < CLEN; tt++) {
      float du = b2f(delta[base + (size_t)tt * DIN]);
      float xv = b2f(xc[base + (size_t)tt * DIN]);
      float dx = du * xv;
      S += du;
      #pragma unroll
      for (int s = 0; s < DST; s++) {
        float a = __expf(du * A_d[s]);
        h[s] = h[s] * a + dx * BCf[tt * 32 + s];
      }
    }
  }
  size_t obase = (((size_t)b * NCHUNK + c) * DST) * DIN + d;
  if (fast) {
    float rS = __expf(-S), a = rS;
    #pragma unroll
    for (int s = 0; s < DST; s++) { P[obase + (size_t)s * DIN] = a; a *= rS; }
  } else {
    #pragma unroll
    for (int s = 0; s < DST; s++) P[obase + (size_t)s * DIN] = __expf(A_d[s] * S);
  }
  #pragma unroll
  for (int s = 0; s < DST; s++) H[obase + (size_t)s * DIN] = h[s];
}

// ---------------- K7: scan pass B: sequential cross-chunk combine -------------
// NOTE: Hstart aliases P (read P/H before writing Hstart).
__global__ __launch_bounds__(256) void scan_b(
    const float* __restrict__ P, const float* __restrict__ H, float* __restrict__ Hstart)
{
  int i = blockIdx.x * 256 + threadIdx.x;
  if (i >= BATCH * DST * DIN) return;
  int d = i % DIN;
  int s = (i / DIN) % DST;
  int b = i / (DST * DIN);
  float h = 0.f;
  for (int c = 0; c < NCHUNK; c++) {
    size_t idx = (((size_t)b * NCHUNK + c) * DST + s) * DIN + d;
    float p = P[idx];
    float hh = H[idx];
    Hstart[idx] = h;
    h = h * p + hh;
  }
}

// ---------------- K8: scan pass C (256thr/1ch — 24 waves/CU; see R7 note) -----
__global__ __launch_bounds__(256) void scan_c(
    const unsigned short* __restrict__ delta, const unsigned short* __restrict__ xc,
    const unsigned short* __restrict__ dbl, const float* __restrict__ A_log,
    const float* __restrict__ Hstart, const unsigned short* __restrict__ xz,
    const float* __restrict__ Dp, unsigned short* __restrict__ ygate)
{
  __shared__ float BCf[CLEN * 32];
  int blk = blockIdx.x;
  int q = blk % 3, c = (blk / 3) % NCHUNK, b = blk / (3 * NCHUNK);
  int t = threadIdx.x;
  int d = q * 256 + t;
  if (t < CLEN * 4) {
    int tt = t >> 2, g = t & 3;
    v8s raw = *(const v8s*)(dbl + (size_t)(b * LSEQ + c * CLEN + tt) * 64 + DTR + g * 8);
    float* dst = &BCf[tt * 32 + g * 8];
    #pragma unroll
    for (int e = 0; e < 8; e++) dst[e] = b2f((unsigned short)raw[e]);
  }
  __syncthreads();
  float A_d[DST];
  bool fast = true;
  #pragma unroll
  for (int s = 0; s < DST; s++) {
    A_d[s] = -__expf(A_log[d * DST + s]);
    fast = fast && (__builtin_fabsf(A_d[s] + (float)(s + 1)) < 1e-3f * (s + 1));
  }
  size_t obase = (((size_t)b * NCHUNK + c) * DST) * DIN + d;
  float h[DST];
  #pragma unroll
  for (int s = 0; s < DST; s++) h[s] = Hstart[obase + (size_t)s * DIN];
  float Dv = Dp[d];
  size_t base = ((size_t)b * LSEQ + c * CLEN) * DIN + d;
  size_t zbase = ((size_t)b * LSEQ + c * CLEN) * (2 * DIN) + DIN + d;
  if (fast) {
    for (int tt = 0; tt < CLEN; tt++) {
      float du = b2f(delta[base + (size_t)tt * DIN]);
      float xv = b2f(xc[base + (size_t)tt * DIN]);
      float dx = du * xv;
      float r = __expf(-du);
      float Bv[16], Cv[16];
      #pragma unroll
      for (int g = 0; g < 4; g++) {
        *(float4*)&Bv[g * 4] = *(const float4*)&BCf[tt * 32 + g * 4];
        *(float4*)&Cv[g * 4] = *(const float4*)&BCf[tt * 32 + 16 + g * 4];
      }
      float a = r, y = 0.f;
      #pragma unroll
      for (int s = 0; s < DST; s++) {
        h[s] = __builtin_fmaf(h[s], a, dx * Bv[s]);
        y = __builtin_fmaf(h[s], Cv[s], y);
        a *= r;
      }
      float zv = b2f(xz[zbase + (size_t)tt * (2 * DIN)]);
      float g = zv / (1.f + __expf(-zv));
      float o = (y + xv * Dv) * g;
      ygate[base + (size_t)tt * DIN] = f2b(o);
    }
  } else {
    for (int tt = 0; tt < CLEN; tt++) {
      float du = b2f(delta[base + (size_t)tt * DIN]);
      float xv = b2f(xc[base + (size_t)tt * DIN]);
      float dx = du * xv;
      float y = 0.f;
      #pragma unroll
      for (int s = 0; s < DST; s++) {
        float a = __expf(du * A_d[s]);
        h[s] = h[s] * a + dx * BCf[tt * 32 + s];
        y += h[s] * BCf[tt * 32 + 16 + s];
      }
      float zv = b2f(xz[zbase + (size_t)tt * (2 * DIN)]);
      float g = zv / (1.f + __expf(-zv));
      float o = (y + xv * Dv) * g;
      ygate[base + (size_t)tt * DIN] = f2b(o);
    }
  }
}

extern "C" void kernel_launch(void* const* d_in, const int* in_sizes, int n_in,
                              void* d_out, int out_size, void* d_ws, size_t ws_size,
                              hipStream_t stream) {
  const float* x      = (const float*)d_in[0];
  const float* gamma  = (const float*)d_in[1];
  const float* beta   = (const float*)d_in[2];
  const float* W_in   = (const float*)d_in[3];
  const float* conv_w = (const float*)d_in[4];
  const float* conv_b = (const float*)d_in[5];
  const float* W_xprj = (const float*)d_in[6];
  const float* W_dt   = (const float*)d_in[7];
  const float* b_dt   = (const float*)d_in[8];
  const float* A_log  = (const float*)d_in[9];
  const float* Dp     = (const float*)d_in[10];
  const float* W_out  = (const float*)d_in[11];
  float* out = (float*)d_out;

  char* ws = (char*)d_ws;
  size_t off = 0;
  auto take = [&](size_t bytes) -> char* {
    char* p = ws + off;
    off = (off + bytes + 255) & ~(size_t)255;
    return p;
  };
  const int NW_IN = 2 * DIN * NDIM;      // 589824
  const int NW_XP = 56 * DIN;            // 43008
  const int NW_OUT = NDIM * DIN;         // 294912
  unsigned short* Wc_in  = (unsigned short*)take((size_t)NW_IN * 2);
  unsigned short* Wc_xp  = (unsigned short*)take((size_t)NW_XP * 2);
  unsigned short* Wc_out = (unsigned short*)take((size_t)NW_OUT * 2);
  unsigned short* Wc_dt  = (unsigned short*)take((size_t)DIN * 32 * 2);
  float*          mu    = (float*)take((size_t)NTOK * 4);
  float*          rsb   = (float*)take((size_t)NTOK * 4);
  unsigned short* xn    = (unsigned short*)take((size_t)NTOK * NDIM * 2);      // 12.6 MB
  unsigned short* xz    = (unsigned short*)take((size_t)NTOK * 2 * DIN * 2);   // 50.3 MB
  unsigned short* xc    = (unsigned short*)take((size_t)NTOK * DIN * 2);       // 25.2 MB
  unsigned short* dbl   = (unsigned short*)take((size_t)NTOK * 64 * 2);        //  2.1 MB
  unsigned short* delta = (unsigned short*)take((size_t)NTOK * DIN * 2);       // 25.2 MB
  unsigned short* ygate = (unsigned short*)take((size_t)NTOK * DIN * 2);       // 25.2 MB
  float*          P     = (float*)take((size_t)BATCH * NCHUNK * DST * DIN * 4);// 25.2 MB
  float*          H     = (float*)take((size_t)BATCH * NCHUNK * DST * DIN * 4);// 25.2 MB
  float*          Hst   = P;                       // alias (scan_b reads-then-writes)
  (void)ws_size; (void)in_sizes; (void)n_in; (void)out_size;

  // 0. cast weights to bf16 (+ W_dt pad to K=32)
  cast_w<<<(NW_IN + 255) / 256, 256, 0, stream>>>(W_in, Wc_in, NW_IN,
                                                  W_xprj, Wc_xp, NW_XP,
                                                  W_out, Wc_out, NW_OUT,
                                                  W_dt, Wc_dt);
  // 1. LayerNorm (stats, then apply+transpose)
  ln_stats<<<BATCH * (LSEQ / 32), 256, 0, stream>>>(x, mu, rsb);
  ln_apply<<<BATCH * 6 * (LSEQ / 64), 256, 0, stream>>>(x, mu, rsb, gamma, beta, xn);
  // 2. in_proj: (16384,384) x (1536,384)^T -> xz bf16
  gemm128<unsigned short><<<dim3(NTOK / 128, 1536 / 128), 256, 0, stream>>>(xn, Wc_in, xz, NDIM, 1536);
  // 3. causal conv + SiLU -> xc bf16 (register-window, CT tokens/thread)
  conv_silu_w<<<(NTOK / CT) * (DIN / 8) / 256, 256, 0, stream>>>(xz, conv_w, conv_b, xc);
  // 4. x_proj: (16384,768) x (56,768)^T -> dbl bf16 [cols 56..63 zero]
  gemm_bt64<<<dim3(NTOK / 64, 1), 256, 0, stream>>>(xc, Wc_xp, dbl, 56, DIN, 64);
  // 5. dt_proj as MFMA GEMM + fused softplus -> delta bf16
  dt_gemm<<<dim3(NTOK / 128, DIN / 128), 256, 0, stream>>>(dbl, Wc_dt, b_dt, delta);
  // 6-8. chunked selective scan (CLEN=32, NCHUNK=128, 256thr/1ch)
  scan_a<<<BATCH * NCHUNK * 3, 256, 0, stream>>>(delta, xc, dbl, A_log, P, H);
  scan_b<<<(BATCH * DST * DIN + 255) / 256, 256, 0, stream>>>(P, H, Hst);
  scan_c<<<BATCH * NCHUNK * 3, 256, 0, stream>>>(delta, xc, dbl, A_log, Hst, xz, Dp, ygate);
  // 9. out_proj fused with output transpose: out[(b*384+c)*4096+l]
  gemm_out<<<dim3(NDIM / 128, NTOK / 128), 256, 0, stream>>>(Wc_out, ygate, out, DIN);
}